// Round 4
// baseline (526.911 us; speedup 1.0000x reference)
//
#include <hip/hip_runtime.h>

// TopologicalDecoder: B=262144, L=16, H=64, C=8, O=32. f32 in, f32 out.
// All weight/bias accesses use wave-uniform addresses on const __restrict__
// pointers -> compiler should select s_load (SMEM) and feed v_fmac with an
// SGPR operand: no LDS, no ds_read, minimal address VALU.
// Output: x_hat[B,32] at out[0..], router_weights[B,8] at out[B*32..].

__device__ __forceinline__ float gelu_exact(float x) {
    return 0.5f * x * (1.0f + erff(x * 0.7071067811865475f));
}

__global__ __launch_bounds__(256, 4) void topo_decoder(
    const float* __restrict__ zg,  const float* __restrict__ ztx,
    const float* __restrict__ cw,  const float* __restrict__ cb,
    const float* __restrict__ rw,  const float* __restrict__ rb,
    const float* __restrict__ cen, const float* __restrict__ txw,
    const float* __restrict__ txb, const float* __restrict__ lng,
    const float* __restrict__ lnb, const float* __restrict__ w1,
    const float* __restrict__ b1,  const float* __restrict__ w2,
    const float* __restrict__ b2,
    float* __restrict__ out, int B)
{
    const int b = blockIdx.x * 256 + threadIdx.x;
    if (b >= B) return;

    // ---- per-sample latents: 2x float4 each ----
    float z[16], zt[16];
    {
        const float4* pg = reinterpret_cast<const float4*>(zg + (size_t)b * 16);
        const float4* pt = reinterpret_cast<const float4*>(ztx + (size_t)b * 16);
        #pragma unroll
        for (int v = 0; v < 4; v++) {
            float4 a = pg[v];
            z[v * 4 + 0] = a.x; z[v * 4 + 1] = a.y; z[v * 4 + 2] = a.z; z[v * 4 + 3] = a.w;
            float4 t = pt[v];
            zt[v * 4 + 0] = t.x; zt[v * 4 + 1] = t.y; zt[v * 4 + 2] = t.z; zt[v * 4 + 3] = t.w;
        }
    }

    // ---- router ----
    float r2 = 0.f;
    #pragma unroll
    for (int l = 0; l < 16; l++) r2 = fmaf(z[l], z[l], r2);
    const float inv_tau = 1.0f / fmaxf(2.0f * fmaxf(1.0f - r2, 0.001f), 0.01f);

    float scv[8];
    float smax = -1e30f;
    #pragma unroll
    for (int c = 0; c < 8; c++) {
        float dsq = 0.f, csq = 0.f, dotv = 0.f;
        #pragma unroll
        for (int l = 0; l < 16; l++) {
            float cv = cen[c * 16 + l];          // uniform -> s_load
            float d  = z[l] - cv;
            dsq  = fmaf(d, d, dsq);
            csq  = fmaf(cv, cv, csq);
            dotv = fmaf(z[l], rw[c * 16 + l], dotv);
        }
        float denom = (1.0f - r2) * (1.0f - csq);
        float arg   = 1.0f + 2.0f * dsq / (denom + 0.001f);
        float dist  = acoshf(fmaxf(arg, 1.001f));
        float score = (-dist + 0.1f * (dotv + rb[c])) * inv_tau;
        scv[c] = score;
        smax = fmaxf(smax, score);
    }
    float esum = 0.f;
    #pragma unroll
    for (int c = 0; c < 8; c++) { scv[c] = __expf(scv[c] - smax); esum += scv[c]; }
    const float rinv = 1.0f / esum;
    #pragma unroll
    for (int c = 0; c < 8; c++) scv[c] *= rinv;

    // ---- router_weights out (frees scv pressure-wise after chart loop) ----
    {
        float4* pr = reinterpret_cast<float4*>(out + (size_t)B * 32 + (size_t)b * 8);
        pr[0] = make_float4(scv[0], scv[1], scv[2], scv[3]);
        pr[1] = make_float4(scv[4], scv[5], scv[6], scv[7]);
    }

    // ---- h = tex_b + z_tex @ tex_w^T  (zt dies here) ----
    float h[64];
    #pragma unroll
    for (int hh = 0; hh < 64; hh++) {
        float a = txb[hh];
        #pragma unroll
        for (int l = 0; l < 16; l++) a = fmaf(txw[hh * 16 + l], zt[l], a);
        h[hh] = a;
    }

    // ---- + sum_c scv[c]*(chart_w[c] @ z + chart_b[c]) ----
    // c kept dynamic to bound code size (I-cache); addresses stay uniform.
    for (int c = 0; c < 8; c++) {
        const float wc = (c == 0) ? scv[0] : (c == 1) ? scv[1] : (c == 2) ? scv[2]
                       : (c == 3) ? scv[3] : (c == 4) ? scv[4] : (c == 5) ? scv[5]
                       : (c == 6) ? scv[6] : scv[7];
        const float* __restrict__ Wc = cw + c * 1024;
        const float* __restrict__ Bc = cb + c * 64;
        #pragma unroll
        for (int hh = 0; hh < 64; hh++) {
            float d = Bc[hh];
            #pragma unroll
            for (int l = 0; l < 16; l++) d = fmaf(Wc[hh * 16 + l], z[l], d);
            h[hh] = fmaf(wc, d, h[hh]);
        }
    }

    // ---- LayerNorm -> GELU (g1 overwrites h's live range) ----
    float mu = 0.f;
    #pragma unroll
    for (int hh = 0; hh < 64; hh++) mu += h[hh];
    mu *= (1.0f / 64.0f);
    float var = 0.f;
    #pragma unroll
    for (int hh = 0; hh < 64; hh++) { float d = h[hh] - mu; var = fmaf(d, d, var); }
    var *= (1.0f / 64.0f);
    const float rs = rsqrtf(var + 1e-5f);
    float g1[64];
    #pragma unroll
    for (int hh = 0; hh < 64; hh++) {
        float hn = (h[hh] - mu) * rs * lng[hh] + lnb[hh];
        g1[hh] = gelu_exact(hn);
    }

    // ---- h1 = gelu(g1 @ w1^T + b1) ----
    float h1[64];
    #pragma unroll
    for (int j = 0; j < 64; j++) {
        float a = b1[j];
        #pragma unroll
        for (int k = 0; k < 64; k++) a = fmaf(g1[k], w1[j * 64 + k], a);
        h1[j] = gelu_exact(a);
    }

    // ---- x_hat = h1 @ w2^T + b2, store float4 immediately ----
    float4* po = reinterpret_cast<float4*>(out + (size_t)b * 32);
    #pragma unroll
    for (int o4 = 0; o4 < 8; o4++) {
        float acc[4];
        #pragma unroll
        for (int u = 0; u < 4; u++) {
            int o = o4 * 4 + u;
            float a = b2[o];
            #pragma unroll
            for (int j = 0; j < 64; j++) a = fmaf(h1[j], w2[o * 64 + j], a);
            acc[u] = a;
        }
        po[o4] = make_float4(acc[0], acc[1], acc[2], acc[3]);
    }
}

extern "C" void kernel_launch(void* const* d_in, const int* in_sizes, int n_in,
                              void* d_out, int out_size, void* d_ws, size_t ws_size,
                              hipStream_t stream) {
    const int B = in_sizes[0] / 16;
    dim3 grid((B + 255) / 256), block(256);
    hipLaunchKernelGGL(topo_decoder, grid, block, 0, stream,
        (const float*)d_in[0],  (const float*)d_in[1],
        (const float*)d_in[2],  (const float*)d_in[3],
        (const float*)d_in[4],  (const float*)d_in[5],
        (const float*)d_in[6],  (const float*)d_in[7],
        (const float*)d_in[8],  (const float*)d_in[9],
        (const float*)d_in[10], (const float*)d_in[11],
        (const float*)d_in[12], (const float*)d_in[13],
        (const float*)d_in[14],
        (float*)d_out, B);
}

// Round 5
// 200.497 us; speedup vs baseline: 2.6280x; 2.6280x over previous
//
#include <hip/hip_runtime.h>

// TopologicalDecoder via MFMA. B=262144, L=16, H=64, C=8, O=32. f32 in/out.
// GEMM1: U[b,160] @ Waug[160,64], U = [r (x) z | z_tex | pad], bias in f32 epilogue.
// GEMM2: gelu(LN) @ w1^T (A split hi/lo, 2-pass).  GEMM3: h1 @ w2^T (A split, 2-pass).
// MFMA 16x16x32 bf16. A: m=lane&15,k=quad*8+j; B: n=lane&15,k=quad*8+j;
// C/D: col=lane&15,row=quad*4+reg (verified m89/m91/m120 mappings).

typedef __attribute__((ext_vector_type(8))) short short8;
typedef __attribute__((ext_vector_type(4))) float f32x4;

__device__ __forceinline__ unsigned short f2bf(float f) {
    unsigned x = __float_as_uint(f);
    x += 0x7fffu + ((x >> 16) & 1u);  // RNE
    return (unsigned short)(x >> 16);
}
__device__ __forceinline__ float bfhi2f(unsigned short u) {
    return __uint_as_float((unsigned)u << 16);
}
__device__ __forceinline__ float gelu_exact(float x) {
    return 0.5f * x * (1.0f + erff(x * 0.7071067811865475f));
}
// packed-fragment flat short index for B[k][n] matrices (KT = K/32 tiles)
__device__ __forceinline__ int bpack(int k, int n, int KT) {
    return (((n >> 4) * KT + (k >> 5)) * 64 + (n & 15) + (((k & 31) >> 3) << 4)) * 8 + (k & 7);
}

// LDS offsets (bytes)
constexpr int WA_OFF  = 0;       // Waug packed  160*64 bf16 = 20480
constexpr int W1_OFF  = 20480;   // w1^T packed   64*64 bf16 =  8192
constexpr int W2_OFF  = 28672;   // w2^T packed   64*32 bf16 =  4096
constexpr int SCR_OFF = 32768;   // 4 waves * 4096 B (A2/A3 hi+lo)
constexpr int RS_OFF  = 49152;   // r[256][9] f32 = 9216 (pad 8->9: conflict-free)
constexpr int CB_OFF  = 58368;   // chart_b [8][64] f32 = 2048
constexpr int TXB_OFF = 60416;   // tex_b f32 256
constexpr int LNG_OFF = 60672;
constexpr int LNB_OFF = 60928;
constexpr int B1_OFF  = 61184;
constexpr int B2_OFF  = 61440;   // 128
constexpr int SMEM_SZ = 61568;

__global__ __launch_bounds__(256, 2) void topo_mfma(
    const float* __restrict__ zg,  const float* __restrict__ ztx,
    const float* __restrict__ cw,  const float* __restrict__ cb,
    const float* __restrict__ rw,  const float* __restrict__ rb,
    const float* __restrict__ cen, const float* __restrict__ txw,
    const float* __restrict__ txb, const float* __restrict__ lng,
    const float* __restrict__ lnb, const float* __restrict__ w1,
    const float* __restrict__ b1,  const float* __restrict__ w2,
    const float* __restrict__ b2,
    float* __restrict__ out, int Btot)
{
    __shared__ __align__(16) char smem[SMEM_SZ];
    short* WA  = (short*)(smem + WA_OFF);
    short* W1T = (short*)(smem + W1_OFF);
    short* W2T = (short*)(smem + W2_OFF);
    float* RS  = (float*)(smem + RS_OFF);
    float* CBS = (float*)(smem + CB_OFF);
    float* TXBS= (float*)(smem + TXB_OFF);
    float* LNGS= (float*)(smem + LNG_OFF);
    float* LNBS= (float*)(smem + LNB_OFF);
    float* B1S = (float*)(smem + B1_OFF);
    float* B2S = (float*)(smem + B2_OFF);

    const int tid = threadIdx.x;

    // ---- pack weights into MFMA-fragment order (bf16) ----
    for (int idx = tid; idx < 160 * 64; idx += 256) {
        int k = idx >> 6, n = idx & 63;
        float v;
        if (k < 128)      v = cw[(k >> 4) * 1024 + n * 16 + (k & 15)];
        else if (k < 144) v = txw[n * 16 + (k - 128)];
        else              v = 0.f;
        WA[bpack(k, n, 5)] = (short)f2bf(v);
    }
    for (int idx = tid; idx < 64 * 64; idx += 256) {
        int k = idx >> 6, n = idx & 63;
        W1T[bpack(k, n, 2)] = (short)f2bf(w1[n * 64 + k]);
    }
    for (int idx = tid; idx < 64 * 32; idx += 256) {
        int k = idx >> 5, n = idx & 31;
        W2T[bpack(k, n, 2)] = (short)f2bf(w2[n * 64 + k]);
    }
    for (int i = tid; i < 512; i += 256) CBS[i] = cb[i];
    if (tid < 64) { TXBS[tid] = txb[tid]; LNGS[tid] = lng[tid];
                    LNBS[tid] = lnb[tid]; B1S[tid] = b1[tid]; }
    if (tid < 32) B2S[tid] = b2[tid];

    // ---- router (exact f32, own sample) ----
    const long sG = (long)blockIdx.x * 256 + tid;
    {
        float z[16];
        const float4* pg = (const float4*)(zg + sG * 16);
        #pragma unroll
        for (int v = 0; v < 4; v++) {
            float4 a = pg[v];
            z[v*4+0]=a.x; z[v*4+1]=a.y; z[v*4+2]=a.z; z[v*4+3]=a.w;
        }
        float r2 = 0.f;
        #pragma unroll
        for (int l = 0; l < 16; l++) r2 = fmaf(z[l], z[l], r2);
        const float inv_tau = 1.0f / fmaxf(2.0f * fmaxf(1.0f - r2, 0.001f), 0.01f);
        float scv[8]; float smax = -1e30f;
        #pragma unroll
        for (int c = 0; c < 8; c++) {
            float dsq = 0.f, csq = 0.f, dotv = 0.f;
            #pragma unroll
            for (int l = 0; l < 16; l++) {
                float cv = cen[c * 16 + l];
                float d  = z[l] - cv;
                dsq  = fmaf(d, d, dsq);
                csq  = fmaf(cv, cv, csq);
                dotv = fmaf(z[l], rw[c * 16 + l], dotv);
            }
            float denom = (1.0f - r2) * (1.0f - csq);
            float arg   = 1.0f + 2.0f * dsq / (denom + 0.001f);
            float dist  = acoshf(fmaxf(arg, 1.001f));
            float score = (-dist + 0.1f * (dotv + rb[c])) * inv_tau;
            scv[c] = score; smax = fmaxf(smax, score);
        }
        float esum = 0.f;
        #pragma unroll
        for (int c = 0; c < 8; c++) { scv[c] = __expf(scv[c] - smax); esum += scv[c]; }
        const float rinv = 1.0f / esum;
        #pragma unroll
        for (int c = 0; c < 8; c++) { scv[c] *= rinv; RS[tid * 9 + c] = scv[c]; }
        float4* pr = (float4*)(out + (long)Btot * 32 + sG * 8);
        pr[0] = make_float4(scv[0], scv[1], scv[2], scv[3]);
        pr[1] = make_float4(scv[4], scv[5], scv[6], scv[7]);
    }
    __syncthreads();

    const int wv = tid >> 6, lane = tid & 63;
    const int q = lane >> 4, col = lane & 15;
    short* scrHi = (short*)(smem + SCR_OFF) + wv * 2048;
    short* scrLo = scrHi + 1024;

    for (int t = 0; t < 4; t++) {
        const int  mBase = wv * 64 + t * 16;              // local sample base of tile
        const long sA = (long)blockIdx.x * 256 + mBase + col;  // A-row sample (m=col)

        // z/zt half for this lane's quad: l0 = (q&1)*8
        const float4* pz  = (const float4*)(zg  + sA * 16 + ((q & 1) << 3));
        const float4* pzt = (const float4*)(ztx + sA * 16 + ((q & 1) << 3));
        float4 za = pz[0],  zb = pz[1];
        float4 ta = pzt[0], tb = pzt[1];
        float zh[8] = {za.x,za.y,za.z,za.w, zb.x,zb.y,zb.z,zb.w};
        float th[8] = {ta.x,ta.y,ta.z,ta.w, tb.x,tb.y,tb.z,tb.w};

        // ---- A1 fragments: u = r_c * z_l (kt 0..3), zt (kt 4) ----
        short8 A1[5];
        #pragma unroll
        for (int kt = 0; kt < 4; kt++) {
            float rC = RS[(mBase + col) * 9 + 2 * kt + (q >> 1)];
            short8 a;
            #pragma unroll
            for (int j = 0; j < 8; j++) a[j] = (short)f2bf(rC * zh[j]);
            A1[kt] = a;
        }
        {
            short8 a;
            #pragma unroll
            for (int j = 0; j < 8; j++) a[j] = (q < 2) ? (short)f2bf(th[j]) : (short)0;
            A1[4] = a;
        }

        // ---- GEMM1: C1[nt] = U @ Waug ----
        f32x4 C1[4];
        #pragma unroll
        for (int nt = 0; nt < 4; nt++) {
            f32x4 acc = {0.f, 0.f, 0.f, 0.f};
            #pragma unroll
            for (int kt = 0; kt < 5; kt++) {
                short8 bf = *(const short8*)(WA + (nt * 5 + kt) * 512 + lane * 8);
                acc = __builtin_amdgcn_mfma_f32_16x16x32_bf16(A1[kt], bf, acc, 0, 0, 0);
            }
            C1[nt] = acc;
        }

        // ---- f32 bias epilogue: + tex_b + sum_c r_c*cb[c,:] ----
        float h[4][4];  // [nt][reg]; row = q*4+reg, col16 = col + 16nt
        #pragma unroll
        for (int nt = 0; nt < 4; nt++) {
            float tbv = TXBS[nt * 16 + col];
            #pragma unroll
            for (int reg = 0; reg < 4; reg++) h[nt][reg] = C1[nt][reg] + tbv;
        }
        #pragma unroll
        for (int c = 0; c < 8; c++) {
            float rr0 = RS[(mBase + q * 4 + 0) * 9 + c];
            float rr1 = RS[(mBase + q * 4 + 1) * 9 + c];
            float rr2 = RS[(mBase + q * 4 + 2) * 9 + c];
            float rr3 = RS[(mBase + q * 4 + 3) * 9 + c];
            #pragma unroll
            for (int nt = 0; nt < 4; nt++) {
                float cbv = CBS[c * 64 + nt * 16 + col];
                h[nt][0] = fmaf(rr0, cbv, h[nt][0]);
                h[nt][1] = fmaf(rr1, cbv, h[nt][1]);
                h[nt][2] = fmaf(rr2, cbv, h[nt][2]);
                h[nt][3] = fmaf(rr3, cbv, h[nt][3]);
            }
        }

        // ---- LayerNorm across the 64 cols (16 lanes x 4 nt) per row ----
        float mu[4], rsd[4];
        #pragma unroll
        for (int reg = 0; reg < 4; reg++) {
            float s = h[0][reg] + h[1][reg] + h[2][reg] + h[3][reg];
            s += __shfl_xor(s, 1); s += __shfl_xor(s, 2);
            s += __shfl_xor(s, 4); s += __shfl_xor(s, 8);
            mu[reg] = s * (1.0f / 64.0f);
        }
        #pragma unroll
        for (int reg = 0; reg < 4; reg++) {
            float d0 = h[0][reg] - mu[reg], d1 = h[1][reg] - mu[reg];
            float d2 = h[2][reg] - mu[reg], d3 = h[3][reg] - mu[reg];
            float s = d0*d0 + d1*d1 + d2*d2 + d3*d3;
            s += __shfl_xor(s, 1); s += __shfl_xor(s, 2);
            s += __shfl_xor(s, 4); s += __shfl_xor(s, 8);
            rsd[reg] = rsqrtf(s * (1.0f / 64.0f) + 1e-5f);
        }

        // ---- g1 = gelu(hn), split hi/lo, write to scratch in A-frag order ----
        #pragma unroll
        for (int nt = 0; nt < 4; nt++) {
            float gv = LNGS[nt * 16 + col], bv = LNBS[nt * 16 + col];
            #pragma unroll
            for (int reg = 0; reg < 4; reg++) {
                float hn = (h[nt][reg] - mu[reg]) * rsd[reg] * gv + bv;
                float g = gelu_exact(hn);
                unsigned short hi = f2bf(g);
                unsigned short lo = f2bf(g - bfhi2f(hi));
                int m = q * 4 + reg;
                int si = (nt >> 1) * 512
                       + (m + (((nt & 1) * 2 + ((lane >> 3) & 1)) << 4)) * 8 + (lane & 7);
                scrHi[si] = (short)hi; scrLo[si] = (short)lo;
            }
        }
        asm volatile("s_waitcnt lgkmcnt(0)" ::: "memory");

        short8 A2h[2], A2l[2];
        #pragma unroll
        for (int kt = 0; kt < 2; kt++) {
            A2h[kt] = *(const short8*)(scrHi + kt * 512 + lane * 8);
            A2l[kt] = *(const short8*)(scrLo + kt * 512 + lane * 8);
        }

        // ---- GEMM2: (g1_hi + g1_lo) @ w1^T, + b1, gelu ----
        #pragma unroll
        for (int nt = 0; nt < 4; nt++) {
            f32x4 acc = {0.f, 0.f, 0.f, 0.f};
            #pragma unroll
            for (int kt = 0; kt < 2; kt++) {
                short8 bf = *(const short8*)(W1T + (nt * 2 + kt) * 512 + lane * 8);
                acc = __builtin_amdgcn_mfma_f32_16x16x32_bf16(A2l[kt], bf, acc, 0, 0, 0);
                acc = __builtin_amdgcn_mfma_f32_16x16x32_bf16(A2h[kt], bf, acc, 0, 0, 0);
            }
            float b1v = B1S[nt * 16 + col];
            #pragma unroll
            for (int reg = 0; reg < 4; reg++) {
                float h1v = gelu_exact(acc[reg] + b1v);
                unsigned short hi = f2bf(h1v);
                unsigned short lo = f2bf(h1v - bfhi2f(hi));
                int m = q * 4 + reg;
                int si = (nt >> 1) * 512
                       + (m + (((nt & 1) * 2 + ((lane >> 3) & 1)) << 4)) * 8 + (lane & 7);
                scrHi[si] = (short)hi; scrLo[si] = (short)lo;
            }
        }
        asm volatile("s_waitcnt lgkmcnt(0)" ::: "memory");

        short8 A3h[2], A3l[2];
        #pragma unroll
        for (int kt = 0; kt < 2; kt++) {
            A3h[kt] = *(const short8*)(scrHi + kt * 512 + lane * 8);
            A3l[kt] = *(const short8*)(scrLo + kt * 512 + lane * 8);
        }

        // ---- GEMM3: h1 @ w2^T + b2, store ----
        const long sOutBase = (long)blockIdx.x * 256 + mBase + q * 4;
        #pragma unroll
        for (int nt = 0; nt < 2; nt++) {
            f32x4 acc = {0.f, 0.f, 0.f, 0.f};
            #pragma unroll
            for (int kt = 0; kt < 2; kt++) {
                short8 bf = *(const short8*)(W2T + (nt * 2 + kt) * 512 + lane * 8);
                acc = __builtin_amdgcn_mfma_f32_16x16x32_bf16(A3l[kt], bf, acc, 0, 0, 0);
                acc = __builtin_amdgcn_mfma_f32_16x16x32_bf16(A3h[kt], bf, acc, 0, 0, 0);
            }
            float b2v = B2S[nt * 16 + col];
            #pragma unroll
            for (int reg = 0; reg < 4; reg++)
                out[(sOutBase + reg) * 32 + nt * 16 + col] = acc[reg] + b2v;
        }
    }
}

extern "C" void kernel_launch(void* const* d_in, const int* in_sizes, int n_in,
                              void* d_out, int out_size, void* d_ws, size_t ws_size,
                              hipStream_t stream) {
    const int B = in_sizes[0] / 16;
    dim3 grid(B / 256), block(256);
    hipLaunchKernelGGL(topo_mfma, grid, block, 0, stream,
        (const float*)d_in[0],  (const float*)d_in[1],
        (const float*)d_in[2],  (const float*)d_in[3],
        (const float*)d_in[4],  (const float*)d_in[5],
        (const float*)d_in[6],  (const float*)d_in[7],
        (const float*)d_in[8],  (const float*)d_in[9],
        (const float*)d_in[10], (const float*)d_in[11],
        (const float*)d_in[12], (const float*)d_in[13],
        (const float*)d_in[14],
        (float*)d_out, B);
}

// Round 6
// 179.928 us; speedup vs baseline: 2.9285x; 1.1143x over previous
//
#include <hip/hip_runtime.h>
#include <hip/hip_bf16.h>

// TopologicalDecoder via MFMA. B=262144, L=16, H=64, C=8, O=32. f32 in/out.
// GEMM1: U[b,192] @ Waug[192,64] where U = [r (x) z |16| z_tex |16 pad| r_c (8) | 1 | 23 pad]
//        and Waug = [chart_w | tex_w | 0 | chart_b | tex_b | 0]  -> bias folded into MFMA.
// GEMM2: bf16(gelu(LN(h))) @ w1^T.  GEMM3: bf16(gelu(.+b1)) @ w2^T.  (single-pass bf16)
// MFMA 16x16x32 bf16. A: m=lane&15,k=quad*8+j; B: n=lane&15,k=quad*8+j;
// C/D: col=lane&15,row=quad*4+reg (verified mappings).
// Scratch C->A transpose via wave-private LDS with XOR bank swizzle.

typedef __attribute__((ext_vector_type(8))) short short8;
typedef __attribute__((ext_vector_type(4))) float f32x4;

__device__ __forceinline__ unsigned short f2bf(float f) {
    unsigned x = __float_as_uint(f);
    x += 0x7fffu + ((x >> 16) & 1u);  // RNE
    return (unsigned short)(x >> 16);
}
__device__ __forceinline__ int pkbf(float a, float b) {
    union { __hip_bfloat162 h2; int i; } u;
    u.h2 = __float22bfloat162_rn(make_float2(a, b));   // v_cvt_pk_bf16_f32 on gfx950
    return u.i;
}
// fast GELU (tanh-form): max abs err ~4e-4
__device__ __forceinline__ float gelu_fast(float x) {
    float x2 = x * x;
    float t  = __expf(fmaf(x2, 0.07135481f, 1.5957691f) * x);   // e^{2y}
    float r  = __builtin_amdgcn_rcpf(t + 1.0f);
    return fmaf(-x, r, x);                                       // x*t/(t+1)
}
// packed-fragment flat short index for B[k][n] matrices (KT = K/32 tiles)
__device__ __forceinline__ int bpack(int k, int n, int KT) {
    return (((n >> 4) * KT + (k >> 5)) * 64 + (n & 15) + (((k & 31) >> 3) << 4)) * 8 + (k & 7);
}
// scratch group swizzle: spreads scatter writes across all 32 banks
__device__ __forceinline__ int gswz(int g) {
    return g ^ (((g >> 4) & 3) << 1) ^ ((g >> 3) & 1);
}

// LDS offsets (bytes). Total 54144 -> 3 blocks/CU (12 waves).
constexpr int WA_OFF  = 0;       // Waug packed 192*64 bf16 = 24576
constexpr int W1_OFF  = 24576;   // w1^T packed  64*64 bf16 =  8192
constexpr int W2_OFF  = 32768;   // w2^T packed  64*32 bf16 =  4096
constexpr int SCR_OFF = 36864;   // 4 waves * 1024 shorts   =  8192
constexpr int RS_OFF  = 45056;   // r transposed [8][256] f32 = 8192
constexpr int LNG_OFF = 53248;   // 256
constexpr int LNB_OFF = 53504;   // 256
constexpr int B1_OFF  = 53760;   // 256
constexpr int B2_OFF  = 54016;   // 128
constexpr int SMEM_SZ = 54144;

__global__ __launch_bounds__(256, 2) void topo_mfma(
    const float* __restrict__ zg,  const float* __restrict__ ztx,
    const float* __restrict__ cw,  const float* __restrict__ cb,
    const float* __restrict__ rw,  const float* __restrict__ rb,
    const float* __restrict__ cen, const float* __restrict__ txw,
    const float* __restrict__ txb, const float* __restrict__ lng,
    const float* __restrict__ lnb, const float* __restrict__ w1,
    const float* __restrict__ b1,  const float* __restrict__ w2,
    const float* __restrict__ b2,
    float* __restrict__ out, int Btot)
{
    __shared__ __align__(16) char smem[SMEM_SZ];
    short* WA  = (short*)(smem + WA_OFF);
    short* W1T = (short*)(smem + W1_OFF);
    short* W2T = (short*)(smem + W2_OFF);
    float* RS  = (float*)(smem + RS_OFF);
    float* LNGS= (float*)(smem + LNG_OFF);
    float* LNBS= (float*)(smem + LNB_OFF);
    float* B1S = (float*)(smem + B1_OFF);
    float* B2S = (float*)(smem + B2_OFF);

    const int tid = threadIdx.x;

    // ---- pack weights (+ folded biases) into MFMA-fragment order ----
    for (int idx = tid; idx < 192 * 64; idx += 256) {
        int k = idx >> 6, n = idx & 63;
        float v;
        if (k < 128)       v = cw[(k >> 4) * 1024 + n * 16 + (k & 15)];
        else if (k < 144)  v = txw[n * 16 + (k - 128)];
        else if (k < 160)  v = 0.f;
        else if (k < 168)  v = cb[(k - 160) * 64 + n];
        else if (k == 168) v = txb[n];
        else               v = 0.f;
        WA[bpack(k, n, 6)] = (short)f2bf(v);
    }
    for (int idx = tid; idx < 64 * 64; idx += 256) {
        int k = idx >> 6, n = idx & 63;
        W1T[bpack(k, n, 2)] = (short)f2bf(w1[n * 64 + k]);
    }
    for (int idx = tid; idx < 64 * 32; idx += 256) {
        int k = idx >> 5, n = idx & 31;
        W2T[bpack(k, n, 2)] = (short)f2bf(w2[n * 64 + k]);
    }
    if (tid < 64) { LNGS[tid] = lng[tid]; LNBS[tid] = lnb[tid]; B1S[tid] = b1[tid]; }
    if (tid < 32) B2S[tid] = b2[tid];

    // ---- router (exact f32, own sample) ----
    const long sG = (long)blockIdx.x * 256 + tid;
    {
        float z[16];
        const float4* pg = (const float4*)(zg + sG * 16);
        #pragma unroll
        for (int v = 0; v < 4; v++) {
            float4 a = pg[v];
            z[v*4+0]=a.x; z[v*4+1]=a.y; z[v*4+2]=a.z; z[v*4+3]=a.w;
        }
        float r2 = 0.f;
        #pragma unroll
        for (int l = 0; l < 16; l++) r2 = fmaf(z[l], z[l], r2);
        const float inv_tau = 1.0f / fmaxf(2.0f * fmaxf(1.0f - r2, 0.001f), 0.01f);
        float scv[8]; float smax = -1e30f;
        #pragma unroll
        for (int c = 0; c < 8; c++) {
            float dsq = 0.f, csq = 0.f, dotv = 0.f;
            #pragma unroll
            for (int l = 0; l < 16; l++) {
                float cv = cen[c * 16 + l];
                float d  = z[l] - cv;
                dsq  = fmaf(d, d, dsq);
                csq  = fmaf(cv, cv, csq);
                dotv = fmaf(z[l], rw[c * 16 + l], dotv);
            }
            float denom = (1.0f - r2) * (1.0f - csq);
            float arg   = 1.0f + 2.0f * dsq / (denom + 0.001f);
            float dist  = acoshf(fmaxf(arg, 1.001f));
            float score = (-dist + 0.1f * (dotv + rb[c])) * inv_tau;
            scv[c] = score; smax = fmaxf(smax, score);
        }
        float esum = 0.f;
        #pragma unroll
        for (int c = 0; c < 8; c++) { scv[c] = __expf(scv[c] - smax); esum += scv[c]; }
        const float rinv = 1.0f / esum;
        #pragma unroll
        for (int c = 0; c < 8; c++) { scv[c] *= rinv; RS[c * 256 + tid] = scv[c]; }
        float4* pr = (float4*)(out + (long)Btot * 32 + sG * 8);
        pr[0] = make_float4(scv[0], scv[1], scv[2], scv[3]);
        pr[1] = make_float4(scv[4], scv[5], scv[6], scv[7]);
    }
    __syncthreads();

    const int wv = tid >> 6, lane = tid & 63;
    const int q = lane >> 4, col = lane & 15;
    const int sub = (lane >> 3) & 1, j = lane & 7;
    short* scr = (short*)(smem + SCR_OFF) + wv * 1024;
    union Frag { short8 s; int i[4]; };

    for (int t = 0; t < 4; t++) {
        const int  mBase = wv * 64 + t * 16;
        const int  sL = mBase + col;                       // local sample (A-row m=col)
        const long sA = (long)blockIdx.x * 256 + sL;

        const float4* pz  = (const float4*)(zg  + sA * 16 + ((q & 1) << 3));
        const float4* pzt = (const float4*)(ztx + sA * 16 + ((q & 1) << 3));
        float4 za = pz[0],  zb = pz[1];
        float4 ta = pzt[0], tb = pzt[1];
        float zh[8] = {za.x,za.y,za.z,za.w, zb.x,zb.y,zb.z,zb.w};
        float th[8] = {ta.x,ta.y,ta.z,ta.w, tb.x,tb.y,tb.z,tb.w};

        // ---- A1 fragments (K=192) ----
        short8 A1[6];
        #pragma unroll
        for (int kt = 0; kt < 4; kt++) {
            float rC = RS[(2 * kt + (q >> 1)) * 256 + sL];
            Frag f;
            #pragma unroll
            for (int p = 0; p < 4; p++) f.i[p] = pkbf(rC * zh[2*p], rC * zh[2*p+1]);
            A1[kt] = f.s;
        }
        {   // kt=4: z_tex rows 128..143 (q<2), zeros 144..159
            Frag f;
            #pragma unroll
            for (int p = 0; p < 4; p++) f.i[p] = (q < 2) ? pkbf(th[2*p], th[2*p+1]) : 0;
            A1[4] = f.s;
        }
        {   // kt=5: r_c at k=160..167 (q==0), 1.0 at k=168 (q==1,j==0)
            Frag f;
            if (q == 0) {
                #pragma unroll
                for (int p = 0; p < 4; p++)
                    f.i[p] = pkbf(RS[(2*p) * 256 + sL], RS[(2*p+1) * 256 + sL]);
            } else if (q == 1) {
                f.i[0] = pkbf(1.0f, 0.0f); f.i[1] = 0; f.i[2] = 0; f.i[3] = 0;
            } else {
                f.i[0] = 0; f.i[1] = 0; f.i[2] = 0; f.i[3] = 0;
            }
            A1[5] = f.s;
        }

        // ---- GEMM1 (bias included) ----
        float h[4][4];  // [nt][reg]; row = q*4+reg, col16 = col + 16nt
        #pragma unroll
        for (int nt = 0; nt < 4; nt++) {
            f32x4 acc = {0.f, 0.f, 0.f, 0.f};
            #pragma unroll
            for (int kt = 0; kt < 6; kt++) {
                short8 bf = *(const short8*)(WA + (nt * 6 + kt) * 512 + lane * 8);
                acc = __builtin_amdgcn_mfma_f32_16x16x32_bf16(A1[kt], bf, acc, 0, 0, 0);
            }
            #pragma unroll
            for (int reg = 0; reg < 4; reg++) h[nt][reg] = acc[reg];
        }

        // ---- LayerNorm stats across 64 cols (16 lanes x 4 nt) per row ----
        float mu[4], rsd[4];
        #pragma unroll
        for (int reg = 0; reg < 4; reg++) {
            float s = h[0][reg] + h[1][reg] + h[2][reg] + h[3][reg];
            s += __shfl_xor(s, 1); s += __shfl_xor(s, 2);
            s += __shfl_xor(s, 4); s += __shfl_xor(s, 8);
            mu[reg] = s * (1.0f / 64.0f);
        }
        #pragma unroll
        for (int reg = 0; reg < 4; reg++) {
            float d0 = h[0][reg] - mu[reg], d1 = h[1][reg] - mu[reg];
            float d2 = h[2][reg] - mu[reg], d3 = h[3][reg] - mu[reg];
            float s = d0*d0 + d1*d1 + d2*d2 + d3*d3;
            s += __shfl_xor(s, 1); s += __shfl_xor(s, 2);
            s += __shfl_xor(s, 4); s += __shfl_xor(s, 8);
            rsd[reg] = rsqrtf(s * (1.0f / 64.0f) + 1e-5f);
        }

        // ---- g1 = gelu(LN(h)) -> scratch (bf16, swizzled) ----
        #pragma unroll
        for (int nt = 0; nt < 4; nt++) {
            float gv = LNGS[nt * 16 + col], bv = LNBS[nt * 16 + col];
            int high = (nt & 1) * 2 + sub;
            #pragma unroll
            for (int reg = 0; reg < 4; reg++) {
                float hn = (h[nt][reg] - mu[reg]) * rsd[reg] * gv + bv;
                float g  = gelu_fast(hn);
                int grp  = gswz((q * 4 + reg) + 16 * high);
                scr[(nt >> 1) * 512 + grp * 8 + j] = (short)f2bf(g);
            }
        }
        asm volatile("s_waitcnt lgkmcnt(0)" ::: "memory");

        short8 A2[2];
        {
            int grp = gswz(lane);
            A2[0] = *(const short8*)(scr +       grp * 8);
            A2[1] = *(const short8*)(scr + 512 + grp * 8);
        }

        // ---- GEMM2 + b1 + gelu -> scratch ----
        #pragma unroll
        for (int nt = 0; nt < 4; nt++) {
            f32x4 acc = {0.f, 0.f, 0.f, 0.f};
            #pragma unroll
            for (int kt = 0; kt < 2; kt++) {
                short8 bf = *(const short8*)(W1T + (nt * 2 + kt) * 512 + lane * 8);
                acc = __builtin_amdgcn_mfma_f32_16x16x32_bf16(A2[kt], bf, acc, 0, 0, 0);
            }
            float b1v = B1S[nt * 16 + col];
            int high = (nt & 1) * 2 + sub;
            #pragma unroll
            for (int reg = 0; reg < 4; reg++) {
                float h1v = gelu_fast(acc[reg] + b1v);
                int grp   = gswz((q * 4 + reg) + 16 * high);
                scr[(nt >> 1) * 512 + grp * 8 + j] = (short)f2bf(h1v);
            }
        }
        asm volatile("s_waitcnt lgkmcnt(0)" ::: "memory");

        short8 A3[2];
        {
            int grp = gswz(lane);
            A3[0] = *(const short8*)(scr +       grp * 8);
            A3[1] = *(const short8*)(scr + 512 + grp * 8);
        }

        // ---- GEMM3 + b2, store ----
        const long sOutBase = (long)blockIdx.x * 256 + mBase + q * 4;
        #pragma unroll
        for (int nt = 0; nt < 2; nt++) {
            f32x4 acc = {0.f, 0.f, 0.f, 0.f};
            #pragma unroll
            for (int kt = 0; kt < 2; kt++) {
                short8 bf = *(const short8*)(W2T + (nt * 2 + kt) * 512 + lane * 8);
                acc = __builtin_amdgcn_mfma_f32_16x16x32_bf16(A3[kt], bf, acc, 0, 0, 0);
            }
            float b2v = B2S[nt * 16 + col];
            #pragma unroll
            for (int reg = 0; reg < 4; reg++)
                out[(sOutBase + reg) * 32 + nt * 16 + col] = acc[reg] + b2v;
        }
    }
}

extern "C" void kernel_launch(void* const* d_in, const int* in_sizes, int n_in,
                              void* d_out, int out_size, void* d_ws, size_t ws_size,
                              hipStream_t stream) {
    const int B = in_sizes[0] / 16;
    dim3 grid(B / 256), block(256);
    hipLaunchKernelGGL(topo_mfma, grid, block, 0, stream,
        (const float*)d_in[0],  (const float*)d_in[1],
        (const float*)d_in[2],  (const float*)d_in[3],
        (const float*)d_in[4],  (const float*)d_in[5],
        (const float*)d_in[6],  (const float*)d_in[7],
        (const float*)d_in[8],  (const float*)d_in[9],
        (const float*)d_in[10], (const float*)d_in[11],
        (const float*)d_in[12], (const float*)d_in[13],
        (const float*)d_in[14],
        (float*)d_out, B);
}

// Round 7
// 159.160 us; speedup vs baseline: 3.3106x; 1.1305x over previous
//
#include <hip/hip_runtime.h>
#include <hip/hip_bf16.h>

// TopologicalDecoder via MFMA. B=262144, L=16, H=64, C=8, O=32. f32 in/out.
// GEMM1: U[b,160] @ Waug[160,64], U = [r (x) z (128) | z_tex (16) | r_c (8) | 1 | 7 pad],
//        Waug = [chart_w | tex_w | chart_b | tex_b | 0]  (biases folded into MFMA).
// GEMM2: bf16(gelu(LN(h))) @ w1^T.  GEMM3: bf16(gelu(.+b1)) @ w2^T.
// w1/w2 B-fragments live in registers (built once per wave from global, L2-hit);
// only Waug + per-wave transpose scratch + router weights live in LDS -> 37888 B
// -> 4 blocks/CU resident = entire 1024-block grid, zero tail.
// MFMA 16x16x32 bf16. A: m=lane&15,k=quad*8+j; B: n=lane&15,k=quad*8+j;
// C/D: col=lane&15,row=quad*4+reg (verified mappings).

typedef __attribute__((ext_vector_type(8))) short short8;
typedef __attribute__((ext_vector_type(4))) float f32x4;

__device__ __forceinline__ int pkbf2(float a, float b) {
    union { __hip_bfloat162 h2; int i; } u;
    u.h2 = __float22bfloat162_rn(make_float2(a, b));   // v_cvt_pk_bf16_f32
    return u.i;
}
__device__ __forceinline__ short pkbf1(float a) { return (short)pkbf2(a, 0.f); }

// fast GELU (tanh-form): max abs err ~4e-4
__device__ __forceinline__ float gelu_fast(float x) {
    float x2 = x * x;
    float t  = __expf(fmaf(x2, 0.07135481f, 1.5957691f) * x);
    float r  = __builtin_amdgcn_rcpf(t + 1.0f);
    return fmaf(-x, r, x);
}
// packed-fragment flat short index for B[k][n] matrices (KT = K/32 tiles)
__device__ __forceinline__ int bpack(int k, int n, int KT) {
    return (((n >> 4) * KT + (k >> 5)) * 64 + (n & 15) + (((k & 31) >> 3) << 4)) * 8 + (k & 7);
}
// scratch group swizzle: spreads scatter writes across banks (R6: conflicts halved)
__device__ __forceinline__ int gswz(int g) {
    return g ^ (((g >> 4) & 3) << 1) ^ ((g >> 3) & 1);
}

// LDS layout (bytes): WAug 20480 | scratch 4x2048 | RS f32 [256][9] 9216 = 37888 total
constexpr int SCR_OFF = 20480;
constexpr int RS_OFF  = 28672;
constexpr int SMEM_SZ = 37888;

__global__ __launch_bounds__(256, 2) void topo_mfma(
    const float* __restrict__ zg,  const float* __restrict__ ztx,
    const float* __restrict__ cw,  const float* __restrict__ cb,
    const float* __restrict__ rw,  const float* __restrict__ rb,
    const float* __restrict__ cen, const float* __restrict__ txw,
    const float* __restrict__ txb, const float* __restrict__ lng,
    const float* __restrict__ lnb, const float* __restrict__ w1,
    const float* __restrict__ b1,  const float* __restrict__ w2,
    const float* __restrict__ b2,
    float* __restrict__ out, int Btot)
{
    __shared__ __align__(16) char smem[SMEM_SZ];
    short* WA = (short*)smem;
    float* RS = (float*)(smem + RS_OFF);

    const int tid = threadIdx.x;
    const int wv = tid >> 6, lane = tid & 63;
    const int q = lane >> 4, col = lane & 15;
    const int sub = (lane >> 3) & 1, j = lane & 7;

    // ---- pack Waug (160x64, biases folded) into MFMA B-fragment order ----
    for (int idx = tid; idx < 160 * 64; idx += 256) {
        int k = idx >> 6, n = idx & 63;
        float v;
        if (k < 128)       v = cw[(k >> 4) * 1024 + n * 16 + (k & 15)];
        else if (k < 144)  v = txw[n * 16 + (k - 128)];
        else if (k < 152)  v = cb[(k - 144) * 64 + n];
        else if (k == 152) v = txb[n];
        else               v = 0.f;
        WA[bpack(k, n, 5)] = pkbf1(v);
    }

    // ---- router (exact f32, own sample) ----
    const long sG = (long)blockIdx.x * 256 + tid;
    {
        float z[16];
        const float4* pg = (const float4*)(zg + sG * 16);
        #pragma unroll
        for (int v = 0; v < 4; v++) {
            float4 a = pg[v];
            z[v*4+0]=a.x; z[v*4+1]=a.y; z[v*4+2]=a.z; z[v*4+3]=a.w;
        }
        float r2 = 0.f;
        #pragma unroll
        for (int l = 0; l < 16; l++) r2 = fmaf(z[l], z[l], r2);
        const float inv_tau = 1.0f / fmaxf(2.0f * fmaxf(1.0f - r2, 0.001f), 0.01f);
        float scv[8]; float smax = -1e30f;
        #pragma unroll
        for (int c = 0; c < 8; c++) {
            float dsq = 0.f, csq = 0.f, dotv = 0.f;
            #pragma unroll
            for (int l = 0; l < 16; l++) {
                float cv = cen[c * 16 + l];
                float d  = z[l] - cv;
                dsq  = fmaf(d, d, dsq);
                csq  = fmaf(cv, cv, csq);
                dotv = fmaf(z[l], rw[c * 16 + l], dotv);
            }
            float denom = (1.0f - r2) * (1.0f - csq);
            float arg   = 1.0f + 2.0f * dsq / (denom + 0.001f);
            float dist  = acoshf(fmaxf(arg, 1.001f));
            float score = (-dist + 0.1f * (dotv + rb[c])) * inv_tau;
            scv[c] = score; smax = fmaxf(smax, score);
        }
        float esum = 0.f;
        #pragma unroll
        for (int c = 0; c < 8; c++) { scv[c] = __expf(scv[c] - smax); esum += scv[c]; }
        const float rinv = 1.0f / esum;
        #pragma unroll
        for (int c = 0; c < 8; c++) { scv[c] *= rinv; RS[tid * 9 + c] = scv[c]; }
        float4* pr = (float4*)(out + (long)Btot * 32 + sG * 8);
        pr[0] = make_float4(scv[0], scv[1], scv[2], scv[3]);
        pr[1] = make_float4(scv[4], scv[5], scv[6], scv[7]);
    }

    // ---- per-wave register B-fragments for w1^T, w2^T (from global, once) ----
    short8 W1F[4][2], W2F[2][2];
    {
        const int kb = q * 8;
        #pragma unroll
        for (int nt = 0; nt < 4; nt++) {
            const float* base = w1 + (nt * 16 + col) * 64 + kb;
            #pragma unroll
            for (int kt = 0; kt < 2; kt++) {
                const float4* p = (const float4*)(base + kt * 32);
                float4 a = p[0], b = p[1];
                union { short8 s; int i[4]; } f;
                f.i[0] = pkbf2(a.x, a.y); f.i[1] = pkbf2(a.z, a.w);
                f.i[2] = pkbf2(b.x, b.y); f.i[3] = pkbf2(b.z, b.w);
                W1F[nt][kt] = f.s;
            }
        }
        #pragma unroll
        for (int nt = 0; nt < 2; nt++) {
            const float* base = w2 + (nt * 16 + col) * 64 + kb;
            #pragma unroll
            for (int kt = 0; kt < 2; kt++) {
                const float4* p = (const float4*)(base + kt * 32);
                float4 a = p[0], b = p[1];
                union { short8 s; int i[4]; } f;
                f.i[0] = pkbf2(a.x, a.y); f.i[1] = pkbf2(a.z, a.w);
                f.i[2] = pkbf2(b.x, b.y); f.i[3] = pkbf2(b.z, b.w);
                W2F[nt][kt] = f.s;
            }
        }
    }
    // ---- per-lane epilogue constants (registers, no LDS) ----
    float lngv[4], lnbv[4], b1v[4], b2v[2];
    #pragma unroll
    for (int nt = 0; nt < 4; nt++) {
        lngv[nt] = lng[nt * 16 + col];
        lnbv[nt] = lnb[nt * 16 + col];
        b1v[nt]  = b1[nt * 16 + col];
    }
    b2v[0] = b2[col]; b2v[1] = b2[16 + col];

    __syncthreads();

    short* scr = (short*)(smem + SCR_OFF) + wv * 1024;
    union Frag { short8 s; int i[4]; };

    for (int t = 0; t < 4; t++) {
        const int  mBase = wv * 64 + t * 16;
        const int  sL = mBase + col;                       // local sample (A-row m=col)
        const long sA = (long)blockIdx.x * 256 + sL;

        const float4* pz  = (const float4*)(zg  + sA * 16 + ((q & 1) << 3));
        const float4* pzt = (const float4*)(ztx + sA * 16 + ((q & 1) << 3));
        float4 za = pz[0],  zb = pz[1];
        float4 ta = pzt[0], tb = pzt[1];
        float zh[8] = {za.x,za.y,za.z,za.w, zb.x,zb.y,zb.z,zb.w};
        float th[8] = {ta.x,ta.y,ta.z,ta.w, tb.x,tb.y,tb.z,tb.w};

        // ---- A1 fragments (K=160) ----
        short8 A1[5];
        #pragma unroll
        for (int kt = 0; kt < 4; kt++) {
            float rC = RS[sL * 9 + 2 * kt + (q >> 1)];
            Frag f;
            #pragma unroll
            for (int p = 0; p < 4; p++) f.i[p] = pkbf2(rC * zh[2*p], rC * zh[2*p+1]);
            A1[kt] = f.s;
        }
        {   // kt=4: k=128..143 z_tex (q<2) | k=144..151 r_c (q==2) | k=152 one (q==3)
            Frag f;
            if (q < 2) {
                #pragma unroll
                for (int p = 0; p < 4; p++) f.i[p] = pkbf2(th[2*p], th[2*p+1]);
            } else if (q == 2) {
                #pragma unroll
                for (int p = 0; p < 4; p++)
                    f.i[p] = pkbf2(RS[sL * 9 + 2*p], RS[sL * 9 + 2*p + 1]);
            } else {
                f.i[0] = pkbf2(1.0f, 0.f); f.i[1] = 0; f.i[2] = 0; f.i[3] = 0;
            }
            A1[4] = f.s;
        }

        // ---- GEMM1 (biases folded) ----
        float h[4][4];  // [nt][reg]; row = q*4+reg, col16 = col + 16nt
        #pragma unroll
        for (int nt = 0; nt < 4; nt++) {
            f32x4 acc = {0.f, 0.f, 0.f, 0.f};
            #pragma unroll
            for (int kt = 0; kt < 5; kt++) {
                short8 bf = *(const short8*)(WA + (nt * 5 + kt) * 512 + lane * 8);
                acc = __builtin_amdgcn_mfma_f32_16x16x32_bf16(A1[kt], bf, acc, 0, 0, 0);
            }
            #pragma unroll
            for (int reg = 0; reg < 4; reg++) h[nt][reg] = acc[reg];
        }

        // ---- LayerNorm stats across 64 cols (16 lanes x 4 nt) per row ----
        float mu[4], rsd[4];
        #pragma unroll
        for (int reg = 0; reg < 4; reg++) {
            float s = h[0][reg] + h[1][reg] + h[2][reg] + h[3][reg];
            s += __shfl_xor(s, 1); s += __shfl_xor(s, 2);
            s += __shfl_xor(s, 4); s += __shfl_xor(s, 8);
            mu[reg] = s * (1.0f / 64.0f);
        }
        #pragma unroll
        for (int reg = 0; reg < 4; reg++) {
            float d0 = h[0][reg] - mu[reg], d1 = h[1][reg] - mu[reg];
            float d2 = h[2][reg] - mu[reg], d3 = h[3][reg] - mu[reg];
            float s = d0*d0 + d1*d1 + d2*d2 + d3*d3;
            s += __shfl_xor(s, 1); s += __shfl_xor(s, 2);
            s += __shfl_xor(s, 4); s += __shfl_xor(s, 8);
            rsd[reg] = rsqrtf(s * (1.0f / 64.0f) + 1e-5f);
        }

        // ---- g1 = gelu(LN(h)) -> scratch (bf16, swizzled groups) ----
        #pragma unroll
        for (int nt = 0; nt < 4; nt++) {
            int high = (nt & 1) * 2 + sub;
            #pragma unroll
            for (int reg = 0; reg < 4; reg++) {
                float hn = (h[nt][reg] - mu[reg]) * rsd[reg] * lngv[nt] + lnbv[nt];
                int grp = gswz((q * 4 + reg) + 16 * high);
                scr[(nt >> 1) * 512 + grp * 8 + j] = pkbf1(gelu_fast(hn));
            }
        }
        asm volatile("s_waitcnt lgkmcnt(0)" ::: "memory");

        short8 A2[2];
        {
            int grp = gswz(lane);
            A2[0] = *(const short8*)(scr +       grp * 8);
            A2[1] = *(const short8*)(scr + 512 + grp * 8);
        }

        // ---- GEMM2 + b1 + gelu -> scratch ----
        #pragma unroll
        for (int nt = 0; nt < 4; nt++) {
            f32x4 acc = {0.f, 0.f, 0.f, 0.f};
            acc = __builtin_amdgcn_mfma_f32_16x16x32_bf16(A2[0], W1F[nt][0], acc, 0, 0, 0);
            acc = __builtin_amdgcn_mfma_f32_16x16x32_bf16(A2[1], W1F[nt][1], acc, 0, 0, 0);
            int high = (nt & 1) * 2 + sub;
            #pragma unroll
            for (int reg = 0; reg < 4; reg++) {
                float h1v = gelu_fast(acc[reg] + b1v[nt]);
                int grp = gswz((q * 4 + reg) + 16 * high);
                scr[(nt >> 1) * 512 + grp * 8 + j] = pkbf1(h1v);
            }
        }
        asm volatile("s_waitcnt lgkmcnt(0)" ::: "memory");

        short8 A3[2];
        {
            int grp = gswz(lane);
            A3[0] = *(const short8*)(scr +       grp * 8);
            A3[1] = *(const short8*)(scr + 512 + grp * 8);
        }

        // ---- GEMM3 + b2, store ----
        const long sOutBase = (long)blockIdx.x * 256 + mBase + q * 4;
        #pragma unroll
        for (int nt = 0; nt < 2; nt++) {
            f32x4 acc = {0.f, 0.f, 0.f, 0.f};
            acc = __builtin_amdgcn_mfma_f32_16x16x32_bf16(A3[0], W2F[nt][0], acc, 0, 0, 0);
            acc = __builtin_amdgcn_mfma_f32_16x16x32_bf16(A3[1], W2F[nt][1], acc, 0, 0, 0);
            #pragma unroll
            for (int reg = 0; reg < 4; reg++)
                out[(sOutBase + reg) * 32 + nt * 16 + col] = acc[reg] + b2v[nt];
        }
    }
}

extern "C" void kernel_launch(void* const* d_in, const int* in_sizes, int n_in,
                              void* d_out, int out_size, void* d_ws, size_t ws_size,
                              hipStream_t stream) {
    const int B = in_sizes[0] / 16;
    dim3 grid(B / 256), block(256);
    hipLaunchKernelGGL(topo_mfma, grid, block, 0, stream,
        (const float*)d_in[0],  (const float*)d_in[1],
        (const float*)d_in[2],  (const float*)d_in[3],
        (const float*)d_in[4],  (const float*)d_in[5],
        (const float*)d_in[6],  (const float*)d_in[7],
        (const float*)d_in[8],  (const float*)d_in[9],
        (const float*)d_in[10], (const float*)d_in[11],
        (const float*)d_in[12], (const float*)d_in[13],
        (const float*)d_in[14],
        (float*)d_out, B);
}